// Round 6
// baseline (212.884 us; speedup 1.0000x reference)
//
#include <hip/hip_runtime.h>
#include <stdint.h>

// 3x3 conv s1 p1, NCHW fp32, 64->128 ch, 16x112x112.
// Implicit GEMM on bf16 MFMA with NHWC bf16 x-repack in d_ws:
//   prep:  x (NCHW fp32) -> x_t[(n*12544+p)*64+ic] bf16 ; w -> Wt[tap][oc][ic] bf16 ; 128B zero block
//   conv (R6): 512-thread block, 128oc x 256px tile.
//     - X union (482 rows + zero row, 60.4KB) staged ONCE per block (kills the 9x X restage
//       that dominated R0/R5's per-tap phases; halo cost 1.88 rows/px at 256-px tile).
//     - W: single 16KB LDS buffer. Per tap: read the 8 A-fragments into REGISTERS, then
//       __syncthreads (all waves' reads done), then stage W(tap+1) over the same buffer
//       (2 global_load_lds/thread of L2-hot weights), compute (8 B ds_read + 32 MFMA),
//       __syncthreads (implicit vmcnt(0) drains the tiny W stage - covered by compute).
//     - LDS 78.2KB => 2 blocks/CU = 16 waves/CU; __launch_bounds__(512,4) caps VGPR at 128
//       (per-tap boundary validity packed into a 36-bit mask; B row = pxb + ni*16 + rofs).
//     - Boundary pixels: staging OOB rows -> zero block; tap-dependent w/h wrap -> zero row.
//     - XCD-chunked bijective block swizzle (784 = 8*98).

#define HW     112
#define PIX    12544
#define ICN    64
#define OCN    128
#define TILEP  256
#define PTILES 49
#define NBLK   784
#define NIMG   16

#define XT_BYTES   (NIMG * PIX * ICN * 2)          // 25,690,112
#define WT_OFF     XT_BYTES
#define WT_BYTES   (9 * OCN * ICN * 2)             // 147,456
#define ZG_OFF     (WT_OFF + WT_BYTES)             // 128B zero block
#define XBLK       (NIMG * (PIX / 64))             // 3136 transpose blocks
#define WBLK       72                              // 72 * 1024 = 73728 weight elems

#define XU_LO      113                             // rows below p0 staged
#define XU_DATA    482                             // p0-113 .. p0+368
#define XU_ZROW    482                             // zero row index
#define XU_ROWS    483
#define XU_BYTES   (XU_ROWS * 128)                 // 61,824

typedef __attribute__((ext_vector_type(8))) __bf16 bf16x8;
typedef __attribute__((ext_vector_type(4))) float  f32x4;

__device__ __forceinline__ uint32_t rne_lo(float f) {
    uint32_t u = __builtin_bit_cast(uint32_t, f);
    return (u + 0x7fffu + ((u >> 16) & 1u)) >> 16;
}
__device__ __forceinline__ uint32_t pk2(float a, float b) {
    uint32_t ub = __builtin_bit_cast(uint32_t, b);
    ub = (ub + 0x7fffu + ((ub >> 16) & 1u)) & 0xffff0000u;
    return rne_lo(a) | ub;
}

__device__ __forceinline__ void load_lds16(const void* g, void* l) {
    __builtin_amdgcn_global_load_lds(
        (const __attribute__((address_space(1))) uint32_t*)g,
        (__attribute__((address_space(3))) uint32_t*)l, 16, 0, 0);
}

// ---------------- prep: x transpose+cvt, weight transpose+cvt, zero block ----------------
__global__ void __launch_bounds__(256)
prep(const float* __restrict__ x, const float* __restrict__ w, uint8_t* __restrict__ ws) {
    const int b = blockIdx.x;
    const int t = threadIdx.x;
    uint16_t* xt = (uint16_t*)ws;
    uint16_t* wt = (uint16_t*)(ws + WT_OFF);

    if (b < XBLK) {
        // 64 pixels per block; thread: pixel = t>>2, ic chunk q = t&3 (16 ic each)
        const int n  = b / (PIX / 64);
        const int p0 = (b - n * (PIX / 64)) * 64;
        const int px = t >> 2;
        const int q  = t & 3;
        const float* src = x + ((size_t)n * ICN + q * 16) * PIX + p0 + px;
        float v[16];
#pragma unroll
        for (int i = 0; i < 16; ++i) v[i] = src[(size_t)i * PIX];
        uint4 u0 = make_uint4(pk2(v[0], v[1]),  pk2(v[2], v[3]),
                              pk2(v[4], v[5]),  pk2(v[6], v[7]));
        uint4 u1 = make_uint4(pk2(v[8], v[9]),  pk2(v[10], v[11]),
                              pk2(v[12], v[13]), pk2(v[14], v[15]));
        char* dst = (char*)xt + ((size_t)(n * PIX + p0 + px)) * 128 + q * 32;
        *(uint4*)dst        = u0;
        *(uint4*)(dst + 16) = u1;
    } else {
        const int wb = b - XBLK;
#pragma unroll
        for (int k = 0; k < 4; ++k) {
            int wi = wb * 1024 + k * 256 + t;          // [0, 73728)
            int r  = wi >> 13;
            int oc = (wi >> 6) & 127;
            int ic = wi & 63;
            wt[wi] = (uint16_t)rne_lo(w[oc * 576 + ic * 9 + r]);
        }
        if (wb == 0 && t < 8) ((uint4*)(ws + ZG_OFF))[t] = make_uint4(0, 0, 0, 0);
    }
}

// ---------------- main conv ----------------
__global__ void __launch_bounds__(512, 4)
conv_mfma(const uint8_t* __restrict__ ws, const float* __restrict__ bias,
          float* __restrict__ out) {
    __shared__ __align__(16) uint8_t Xu[XU_BYTES];   // X union, staged once
    __shared__ __align__(16) uint8_t Ws[16384];      // weights, single buffer per tap

    const char* xt = (const char*)ws;
    const char* wt = (const char*)(ws + WT_OFF);
    const char* zg = (const char*)(ws + ZG_OFF);

    const int t = threadIdx.x;
    // Bijective XCD-chunked swizzle: 784 = 8*98.
    const int b = (blockIdx.x & 7) * (NBLK / 8) + (blockIdx.x >> 3);
    const int n_img = b / PTILES;
    const int p0 = (b - n_img * PTILES) * TILEP;

    const int lane = t & 63;
    const int wave = t >> 6;                        // 0..7
    const int lr = lane & 15;
    const int lq = lane >> 4;
    const int oc_base = (wave & 1) * 64;
    const int px_base = (wave >> 1) * 64;           // 0,64,128,192

    // ---- staging geometry: pass covers 64 rows; row = pass*64 + (t>>3); chunk = t&7 ----
    const int rowB  = t >> 3;                        // 0..63 ; pass*64 ≡ 0 mod 8
    const int cswz8 = ((t & 7) ^ (rowB & 7)) * 16;
    const char* zaddr = zg + (t & 7) * 16;

    // ---- stage X union once: row r holds pixel p0-113+r (OOB -> zero block) ----
    {
        const char* xsrc = xt + ((ptrdiff_t)(n_img * PIX + p0 - XU_LO)) * 128 + cswz8;
#pragma unroll
        for (int r2 = 0; r2 < 8; ++r2) {
            int r = r2 * 64 + rowB;
            if (r2 < 7 || r < XU_DATA) {
                int pr = p0 - XU_LO + r;
                const char* gp = ((unsigned)pr < PIX) ? (xsrc + (ptrdiff_t)r * 128) : zaddr;
                load_lds16(gp, (char*)Xu + r2 * 8192 + wave * 1024);
            }
        }
        if (t < 8)   // zero row
            *(uint4*)((char*)Xu + XU_ZROW * 128 + t * 16) = make_uint4(0, 0, 0, 0);
    }

    // ---- stage weights tap 0 ----
    const char* wsrc = wt + rowB * 128 + cswz8;     // + tap*16384 + r2*8192
#pragma unroll
    for (int r2 = 0; r2 < 2; ++r2)
        load_lds16(wsrc + r2 * 8192, (char*)Ws + r2 * 8192 + wave * 1024);

    // ---- per-tap boundary validity packed into 36 bits; B row = pxb + ni*16 + rofs ----
    const int pxb = px_base + lr + XU_LO;
    uint64_t vmask = 0;
    {
#pragma unroll
        for (int ni = 0; ni < 4; ++ni) {
            int p = p0 + px_base + ni * 16 + lr;
            int h = p / HW;
            int w = p - h * HW;
#pragma unroll
            for (int tap = 0; tap < 9; ++tap) {
                int dy = tap / 3 - 1;
                int dx = tap - (tap / 3) * 3 - 1;
                uint64_t ok = (((unsigned)(h + dy) < HW) & ((unsigned)(w + dx) < HW)) ? 1u : 0u;
                vmask |= ok << (tap * 4 + ni);
            }
        }
    }

    f32x4 acc[4][4];
    {
        f32x4 z = {0.f, 0.f, 0.f, 0.f};
#pragma unroll
        for (int i = 0; i < 4; ++i)
#pragma unroll
            for (int j = 0; j < 4; ++j) acc[i][j] = z;
    }

    __syncthreads();   // all staging drained (vmcnt(0)+lgkmcnt(0)) + barrier

#pragma unroll
    for (int tap = 0; tap < 9; ++tap) {
        const int dy = tap / 3 - 1;
        const int dx = tap - (tap / 3) * 3 - 1;
        const int rofs = dy * HW + dx;

        // A-fragments for this tap -> registers (must complete before Ws is overwritten)
        bf16x8 a0[4], a1[4];
#pragma unroll
        for (int mi = 0; mi < 4; ++mi) {
            int R = oc_base + mi * 16 + lr;
            const char* wa = (const char*)Ws + R * 128;
            a0[mi] = *(const bf16x8*)(wa + ((lq       ^ (R & 7)) * 16));
            a1[mi] = *(const bf16x8*)(wa + (((4 + lq) ^ (R & 7)) * 16));
        }

        __syncthreads();   // lgkmcnt(0): every wave's A-reads done; vmcnt already 0

        // stage next tap's weights over Ws (2 loads/thread of L2-hot data)
        if (tap < 8) {
#pragma unroll
            for (int r2 = 0; r2 < 2; ++r2)
                load_lds16(wsrc + (tap + 1) * 16384 + r2 * 8192,
                           (char*)Ws + r2 * 8192 + wave * 1024);
        }

        // boundary: redirect invalid rows to the zero row
        int ro[4];
#pragma unroll
        for (int ni = 0; ni < 4; ++ni) {
            bool ok = (vmask >> (tap * 4 + ni)) & 1;
            ro[ni] = ok ? (pxb + ni * 16 + rofs) : XU_ZROW;
        }

        // ---- kh = 0 ----
        {
            bf16x8 bf[4];
#pragma unroll
            for (int ni = 0; ni < 4; ++ni)
                bf[ni] = *(const bf16x8*)((const char*)Xu + ro[ni] * 128
                                          + ((lq ^ (ro[ni] & 7)) * 16));
#pragma unroll
            for (int mi = 0; mi < 4; ++mi)
#pragma unroll
                for (int ni = 0; ni < 4; ++ni)
                    acc[mi][ni] = __builtin_amdgcn_mfma_f32_16x16x32_bf16(
                        a0[mi], bf[ni], acc[mi][ni], 0, 0, 0);
        }
        // ---- kh = 1 ----
        {
            bf16x8 bf[4];
#pragma unroll
            for (int ni = 0; ni < 4; ++ni)
                bf[ni] = *(const bf16x8*)((const char*)Xu + ro[ni] * 128
                                          + (((4 + lq) ^ (ro[ni] & 7)) * 16));
#pragma unroll
            for (int mi = 0; mi < 4; ++mi)
#pragma unroll
                for (int ni = 0; ni < 4; ++ni)
                    acc[mi][ni] = __builtin_amdgcn_mfma_f32_16x16x32_bf16(
                        a1[mi], bf[ni], acc[mi][ni], 0, 0, 0);
        }

        // implicit vmcnt(0) drains the W stage (issued before 8 ds_read + 32 MFMA),
        // barrier releases Ws for the next tap's A-reads.
        if (tap < 8) __syncthreads();
    }

    // ---- epilogue: D col = lane&15 -> pixel, row = lq*4+reg -> oc (validated R1)
#pragma unroll
    for (int mi = 0; mi < 4; ++mi) {
#pragma unroll
        for (int rg = 0; rg < 4; ++rg) {
            const int oc = oc_base + mi * 16 + lq * 4 + rg;
            const float bb = bias[oc];
            float* orow = out + ((size_t)n_img * OCN + oc) * PIX + p0 + px_base + lr;
#pragma unroll
            for (int ni = 0; ni < 4; ++ni)
                orow[ni * 16] = acc[mi][ni][rg] + bb;
        }
    }
}

extern "C" void kernel_launch(void* const* d_in, const int* in_sizes, int n_in,
                              void* d_out, int out_size, void* d_ws, size_t ws_size,
                              hipStream_t stream) {
    const float* x    = (const float*)d_in[0];
    const float* w    = (const float*)d_in[1];
    const float* bias = (const float*)d_in[2];
    float* out = (float*)d_out;
    uint8_t* ws = (uint8_t*)d_ws;   // needs ZG_OFF + 128 = 25,837,696 bytes

    prep<<<XBLK + WBLK, 256, 0, stream>>>(x, w, ws);
    conv_mfma<<<NBLK, 512, 0, stream>>>(ws, bias, out);
}

// Round 7
// 175.396 us; speedup vs baseline: 1.2137x; 1.2137x over previous
//
#include <hip/hip_runtime.h>
#include <stdint.h>

// 3x3 conv s1 p1, NCHW fp32, 64->128 ch, 16x112x112.
// Implicit GEMM on bf16 MFMA with NHWC bf16 x-repack in d_ws:
//   prep (R7): x (NCHW fp32) -> x_t[(n*12544+p)*64+ic] bf16 via WIDE loads:
//       784 blocks x 256px tile; thread = 4px (float4) x 16 ic-planes -> per wave
//       instruction 4 x 256B contiguous segments (was 4 x 64B), 16 loads in flight.
//       R1/R2 arithmetic showed prep ~45-50us (~3.5x its 13us BW floor) - read
//       granularity was the suspect. Same xt byte layout as before (u0/u1 @ q*32).
//   conv (unchanged R5 best): per block 128oc x 128px tile; 9 taps, double-buffered
//       As/Xs with counted-vmcnt pipeline (raw s_barrier, vmcnt(8)); XCD swizzle.

#define HW     112
#define PIX    12544
#define ICN    64
#define OCN    128
#define TILEP  128
#define PTILES 98
#define NBLK   1568
#define NIMG   16

#define XT_BYTES   (NIMG * PIX * ICN * 2)          // 25,690,112
#define WT_OFF     XT_BYTES
#define WT_BYTES   (9 * OCN * ICN * 2)             // 147,456
#define ZG_OFF     (WT_OFF + WT_BYTES)             // 128B zero block
#define XBLK       (NIMG * (PIX / 256))            // 784 transpose blocks (256px each)
#define WBLK       72                              // 72 * 1024 = 73728 weight elems

typedef __attribute__((ext_vector_type(8))) __bf16 bf16x8;
typedef __attribute__((ext_vector_type(4))) float  f32x4;

__device__ __forceinline__ uint32_t rne_lo(float f) {
    uint32_t u = __builtin_bit_cast(uint32_t, f);
    return (u + 0x7fffu + ((u >> 16) & 1u)) >> 16;
}
__device__ __forceinline__ uint32_t pk2(float a, float b) {
    uint32_t ub = __builtin_bit_cast(uint32_t, b);
    ub = (ub + 0x7fffu + ((ub >> 16) & 1u)) & 0xffff0000u;
    return rne_lo(a) | ub;
}

__device__ __forceinline__ void load_lds16(const void* g, void* l) {
    __builtin_amdgcn_global_load_lds(
        (const __attribute__((address_space(1))) uint32_t*)g,
        (__attribute__((address_space(3))) uint32_t*)l, 16, 0, 0);
}

// ---------------- prep: x transpose+cvt (wide), weight transpose+cvt, zero block ----------------
__global__ void __launch_bounds__(256)
prep(const float* __restrict__ x, const float* __restrict__ w, uint8_t* __restrict__ ws) {
    const int b = blockIdx.x;
    const int t = threadIdx.x;
    uint16_t* xt = (uint16_t*)ws;
    uint16_t* wt = (uint16_t*)(ws + WT_OFF);

    if (b < XBLK) {
        // 256 px per block; thread: px group g = t>>2 (4 px via float4), ic chunk q = t&3
        const int n  = b / (PIX / 256);
        const int p0 = (b - n * (PIX / 256)) * 256;
        const int g  = t >> 2;
        const int q  = t & 3;
        const float* src = x + ((size_t)n * ICN + q * 16) * PIX + p0 + g * 4;
        float4 v[16];
#pragma unroll
        for (int i = 0; i < 16; ++i)
            v[i] = *(const float4*)(src + (size_t)i * PIX);
        char* dst0 = (char*)xt + ((size_t)(n * PIX + p0 + g * 4)) * 128 + q * 32;
#pragma unroll
        for (int j = 0; j < 4; ++j) {
            float vj[16];
#pragma unroll
            for (int i = 0; i < 16; ++i) vj[i] = (&v[i].x)[j];
            uint4 u0 = make_uint4(pk2(vj[0], vj[1]),   pk2(vj[2], vj[3]),
                                  pk2(vj[4], vj[5]),   pk2(vj[6], vj[7]));
            uint4 u1 = make_uint4(pk2(vj[8], vj[9]),   pk2(vj[10], vj[11]),
                                  pk2(vj[12], vj[13]), pk2(vj[14], vj[15]));
            char* dst = dst0 + (size_t)j * 128;
            *(uint4*)dst        = u0;
            *(uint4*)(dst + 16) = u1;
        }
    } else {
        const int wb = b - XBLK;
#pragma unroll
        for (int k = 0; k < 4; ++k) {
            int wi = wb * 1024 + k * 256 + t;          // [0, 73728)
            int r  = wi >> 13;
            int oc = (wi >> 6) & 127;
            int ic = wi & 63;
            wt[wi] = (uint16_t)rne_lo(w[oc * 576 + ic * 9 + r]);
        }
        if (wb == 0 && t < 8) ((uint4*)(ws + ZG_OFF))[t] = make_uint4(0, 0, 0, 0);
    }
}

// ---------------- main conv (unchanged from R5) ----------------
__global__ void __launch_bounds__(256)
conv_mfma(const uint8_t* __restrict__ ws, const float* __restrict__ bias,
          float* __restrict__ out) {
    __shared__ uint16_t As[2][8192];   // [buf][oc 0..127][ic chunk swizzled] 128B rows
    __shared__ uint16_t Xs[2][8192];   // [buf][px 0..127][ic chunk swizzled] 128B rows

    const char* xt = (const char*)ws;
    const char* wt = (const char*)(ws + WT_OFF);
    const char* zg = (const char*)(ws + ZG_OFF);

    const int t = threadIdx.x;
    // Bijective XCD-chunked swizzle: XCD k (blockIdx%8) gets contiguous tile ids.
    const int b = (blockIdx.x & 7) * (NBLK / 8) + (blockIdx.x >> 3);
    const int n_img = b / PTILES;
    const int p0 = (b - n_img * PTILES) * TILEP;

    const int lane = t & 63;
    const int wave = t >> 6;
    const int lr = lane & 15;
    const int lq = lane >> 4;
    const int oc_base = (wave & 1) * 64;
    const int px_base = (wave >> 1) * 64;

    // ---- staging geometry: slot = r2*256 + t; row = r2*32 + (t>>3); cpos = t&7
    const int rowB = t >> 3;                   // 0..31
    const int cswz = (t & 7) ^ (rowB & 7);     // row&7 == rowB&7 (r2*32 = 0 mod 8)
    int sh[4], sw[4];
    const char* xaddr[4];
#pragma unroll
    for (int r2 = 0; r2 < 4; ++r2) {
        int row = r2 * 32 + rowB;
        int p = p0 + row;
        int hh = p / HW;
        sh[r2] = hh;
        sw[r2] = p - hh * HW;
        xaddr[r2] = xt + ((size_t)(n_img * PIX + p)) * 128 + cswz * 16;
    }
    const char* waddr0 = wt + rowB * 128 + cswz * 16;
    const char* zaddr  = zg + (t & 7) * 16;

    // stage tap T into buffer bsel: exactly 8 global_load_lds per thread (4 W + 4 X)
    auto stage = [&](int tap, int bsel) {
        const int dy = tap / 3 - 1;
        const int dx = tap - (tap / 3) * 3 - 1;
        const int toff = (dy * HW + dx) * 128;
#pragma unroll
        for (int r2 = 0; r2 < 4; ++r2)
            load_lds16(waddr0 + tap * 16384 + r2 * 4096,
                       (char*)As[bsel] + r2 * 4096 + wave * 1024);
#pragma unroll
        for (int r2 = 0; r2 < 4; ++r2) {
            int hh = sh[r2] + dy;
            int wwp = sw[r2] + dx;
            bool ok = ((unsigned)hh < HW) & ((unsigned)wwp < HW);
            const char* gp = ok ? (xaddr[r2] + toff) : zaddr;
            load_lds16(gp, (char*)Xs[bsel] + r2 * 4096 + wave * 1024);
        }
    };

    f32x4 acc[4][4];
    {
        f32x4 z = {0.f, 0.f, 0.f, 0.f};
#pragma unroll
        for (int i = 0; i < 4; ++i)
#pragma unroll
            for (int j = 0; j < 4; ++j) acc[i][j] = z;
    }

    // prologue: tap 0 -> buf 0 (stays in flight; waited at iteration 0's vmcnt)
    stage(0, 0);

#pragma unroll
    for (int tap = 0; tap < 9; ++tap) {
        // B1: everyone finished reading buf^1 (= compute(tap-1)); safe to overwrite.
        __builtin_amdgcn_sched_barrier(0);
        __builtin_amdgcn_s_barrier();

        if (tap < 8) stage(tap + 1, (tap + 1) & 1);
        __builtin_amdgcn_sched_barrier(0);
        if (tap < 8) asm volatile("s_waitcnt vmcnt(8)" ::: "memory");   // tap's 8 landed
        else         asm volatile("s_waitcnt vmcnt(0)" ::: "memory");   // last tap: drain
        __builtin_amdgcn_sched_barrier(0);

        // B2: all waves' tap data in LDS (each passed its own counted wait).
        __builtin_amdgcn_s_barrier();

        const char* Ab = (const char*)As[tap & 1];
        const char* Xb = (const char*)Xs[tap & 1];
#pragma unroll
        for (int kh = 0; kh < 2; ++kh) {
            bf16x8 a_frag[4], b_frag[4];
            const int cc = kh * 4 + lq;
#pragma unroll
            for (int mi = 0; mi < 4; ++mi) {
                int R = oc_base + mi * 16 + lr;
                a_frag[mi] = *(const bf16x8*)(Ab + R * 128 + ((cc ^ (R & 7)) * 16));
            }
#pragma unroll
            for (int ni = 0; ni < 4; ++ni) {
                int R = px_base + ni * 16 + lr;
                b_frag[ni] = *(const bf16x8*)(Xb + R * 128 + ((cc ^ (R & 7)) * 16));
            }
#pragma unroll
            for (int mi = 0; mi < 4; ++mi)
#pragma unroll
                for (int ni = 0; ni < 4; ++ni)
                    acc[mi][ni] = __builtin_amdgcn_mfma_f32_16x16x32_bf16(
                        a_frag[mi], b_frag[ni], acc[mi][ni], 0, 0, 0);
        }
    }

    // ---- epilogue: D col = lane&15 -> pixel, row = lq*4+reg -> oc (validated R1)
#pragma unroll
    for (int mi = 0; mi < 4; ++mi) {
#pragma unroll
        for (int rg = 0; rg < 4; ++rg) {
            const int oc = oc_base + mi * 16 + lq * 4 + rg;
            const float bb = bias[oc];
            float* orow = out + ((size_t)n_img * OCN + oc) * PIX + p0 + px_base + lr;
#pragma unroll
            for (int ni = 0; ni < 4; ++ni)
                orow[ni * 16] = acc[mi][ni][rg] + bb;
        }
    }
}

extern "C" void kernel_launch(void* const* d_in, const int* in_sizes, int n_in,
                              void* d_out, int out_size, void* d_ws, size_t ws_size,
                              hipStream_t stream) {
    const float* x    = (const float*)d_in[0];
    const float* w    = (const float*)d_in[1];
    const float* bias = (const float*)d_in[2];
    float* out = (float*)d_out;
    uint8_t* ws = (uint8_t*)d_ws;   // needs ZG_OFF + 128 = 25,837,696 bytes

    prep<<<XBLK + WBLK, 256, 0, stream>>>(x, w, ws);
    conv_mfma<<<NBLK, 256, 0, stream>>>(ws, bias, out);
}

// Round 8
// 172.143 us; speedup vs baseline: 1.2367x; 1.0189x over previous
//
#include <hip/hip_runtime.h>
#include <stdint.h>

// 3x3 conv s1 p1, NCHW fp32, 64->128 ch, 16x112x112.
// Implicit GEMM on bf16 MFMA with NHWC bf16 x-repack in d_ws:
//   prep (R0-proven): x (NCHW fp32) -> x_t[(n*12544+p)*64+ic] bf16 ; w -> Wt[tap][oc][ic] bf16.
//   conv (R8): per block 128oc x 128px tile.
//     - X staged as per-dy WINDOW (160 row-slots covering the 130 needed rows, dbuf) -> only
//       3 X stages per block instead of 9 (B-frag row = (p-p0)+1+dx, dy absorbed in window base).
//     - W double-buffered 16KB/tap, counted-vmcnt pipeline (R5-proven skeleton, raw s_barrier,
//       no vmcnt(0) drains). Mixed issue schedule -> per-tap waits {9,9,4,9,9,4,4,4,0}.
//     - Staged volume 288->194 KB/block, VMEM instr 80->51/thread, same ds_read/MFMA/barriers.
//     - T5 s_setprio(1) around MFMA clusters (2 independent blocks/CU arbitration).
//     - Boundary: staging OOB pixel -> zero block; tap-dependent h/w wrap -> zero row 160.
//     - XCD-chunked bijective block swizzle (1568 = 8*196).

#define HW     112
#define PIX    12544
#define ICN    64
#define OCN    128
#define TILEP  128
#define PTILES 98
#define NBLK   1568
#define NIMG   16

#define XT_BYTES   (NIMG * PIX * ICN * 2)          // 25,690,112
#define WT_OFF     XT_BYTES
#define WT_BYTES   (9 * OCN * ICN * 2)             // 147,456
#define ZG_OFF     (WT_OFF + WT_BYTES)             // 128B zero block
#define XBLK       (NIMG * (PIX / 64))             // 3136 transpose blocks
#define WBLK       72                              // 72 * 1024 = 73728 weight elems

#define XW_ZROW    160                             // zero row index (slots 0..159 staged)
#define XW_BYTES   (161 * 128)                     // 20,608 per buffer

typedef __attribute__((ext_vector_type(8))) __bf16 bf16x8;
typedef __attribute__((ext_vector_type(4))) float  f32x4;

__device__ __forceinline__ uint32_t rne_lo(float f) {
    uint32_t u = __builtin_bit_cast(uint32_t, f);
    return (u + 0x7fffu + ((u >> 16) & 1u)) >> 16;
}
__device__ __forceinline__ uint32_t pk2(float a, float b) {
    uint32_t ub = __builtin_bit_cast(uint32_t, b);
    ub = (ub + 0x7fffu + ((ub >> 16) & 1u)) & 0xffff0000u;
    return rne_lo(a) | ub;
}

__device__ __forceinline__ void load_lds16(const void* g, void* l) {
    __builtin_amdgcn_global_load_lds(
        (const __attribute__((address_space(1))) uint32_t*)g,
        (__attribute__((address_space(3))) uint32_t*)l, 16, 0, 0);
}

// ---------------- prep: x transpose+cvt, weight transpose+cvt, zero block ----------------
__global__ void __launch_bounds__(256)
prep(const float* __restrict__ x, const float* __restrict__ w, uint8_t* __restrict__ ws) {
    const int b = blockIdx.x;
    const int t = threadIdx.x;
    uint16_t* xt = (uint16_t*)ws;
    uint16_t* wt = (uint16_t*)(ws + WT_OFF);

    if (b < XBLK) {
        // 64 pixels per block; thread: pixel = t>>2, ic chunk q = t&3 (16 ic each)
        const int n  = b / (PIX / 64);
        const int p0 = (b - n * (PIX / 64)) * 64;
        const int px = t >> 2;
        const int q  = t & 3;
        const float* src = x + ((size_t)n * ICN + q * 16) * PIX + p0 + px;
        float v[16];
#pragma unroll
        for (int i = 0; i < 16; ++i) v[i] = src[(size_t)i * PIX];
        uint4 u0 = make_uint4(pk2(v[0], v[1]),  pk2(v[2], v[3]),
                              pk2(v[4], v[5]),  pk2(v[6], v[7]));
        uint4 u1 = make_uint4(pk2(v[8], v[9]),  pk2(v[10], v[11]),
                              pk2(v[12], v[13]), pk2(v[14], v[15]));
        char* dst = (char*)xt + ((size_t)(n * PIX + p0 + px)) * 128 + q * 32;
        *(uint4*)dst        = u0;
        *(uint4*)(dst + 16) = u1;
    } else {
        const int wb = b - XBLK;
#pragma unroll
        for (int k = 0; k < 4; ++k) {
            int wi = wb * 1024 + k * 256 + t;          // [0, 73728)
            int r  = wi >> 13;
            int oc = (wi >> 6) & 127;
            int ic = wi & 63;
            wt[wi] = (uint16_t)rne_lo(w[oc * 576 + ic * 9 + r]);
        }
        if (wb == 0 && t < 8) ((uint4*)(ws + ZG_OFF))[t] = make_uint4(0, 0, 0, 0);
    }
}

// ---------------- main conv ----------------
__global__ void __launch_bounds__(256)
conv_mfma(const uint8_t* __restrict__ ws, const float* __restrict__ bias,
          float* __restrict__ out) {
    __shared__ uint16_t As[2][8192];                   // W, dbuf, 16KB each
    __shared__ __align__(16) uint8_t Xw[2][XW_BYTES];  // X per-dy window, dbuf

    const char* xt = (const char*)ws;
    const char* wt = (const char*)(ws + WT_OFF);
    const char* zg = (const char*)(ws + ZG_OFF);

    const int t = threadIdx.x;
    // Bijective XCD-chunked swizzle: XCD k (blockIdx%8) gets contiguous tile ids.
    const int b = (blockIdx.x & 7) * (NBLK / 8) + (blockIdx.x >> 3);
    const int n_img = b / PTILES;
    const int p0 = (b - n_img * PTILES) * TILEP;

    const int lane = t & 63;
    const int wave = t >> 6;
    const int lr = lane & 15;
    const int lq = lane >> 4;
    const int oc_base = (wave & 1) * 64;
    const int px_base = (wave >> 1) * 64;

    // ---- staging geometry: row = r2*32 + (t>>3); chunk pos = t&7, src chunk XOR-swizzled
    const int rowB = t >> 3;                   // 0..31
    const int cswz = (t & 7) ^ (rowB & 7);     // row&7 == rowB&7 (r2*32 = 0 mod 8)
    const char* xsrcX  = xt + ((size_t)n_img * PIX) * 128 + cswz * 16;  // + pw*128
    const char* waddr0 = wt + rowB * 128 + cswz * 16;
    const char* zaddr  = zg + (t & 7) * 16;

    // ---- per-ni output-pixel geometry; window row = (p - p0) + 1 + dx (dy-independent) ----
    int hh[4], wwp[4], rbase[4];
#pragma unroll
    for (int ni = 0; ni < 4; ++ni) {
        int po = px_base + ni * 16 + lr;
        int p  = p0 + po;
        int h  = p / HW;
        hh[ni]   = h;
        wwp[ni]  = p - h * HW;
        rbase[ni] = po + 1;
    }

    // stage W for tap -> As[bsel]: 4 loads/thread (16KB)
    auto stageW = [&](int tap, int bsel) {
#pragma unroll
        for (int r2 = 0; r2 < 4; ++r2)
            load_lds16(waddr0 + tap * 16384 + r2 * 4096,
                       (char*)As[bsel] + r2 * 4096 + wave * 1024);
    };
    // stage X window for dy-group g -> Xw[bsel]: 5 loads/thread (160 row-slots; rows
    // 0..129 are the live window, 130..159 harmless over-stage; OOB pixels -> zero block)
    auto stageX = [&](int g, int bsel) {
        const int pwb = p0 + (g - 1) * HW - 1;         // window row 0 = pixel pwb
#pragma unroll
        for (int r2 = 0; r2 < 5; ++r2) {
            int pw = pwb + r2 * 32 + rowB;
            const char* gp = ((unsigned)pw < PIX) ? (xsrcX + (ptrdiff_t)pw * 128) : zaddr;
            load_lds16(gp, (char*)Xw[bsel] + r2 * 4096 + wave * 1024);
        }
    };

    // zero rows of both window buffers (never overwritten by staging: slots stop at 159)
    if (t < 16)
        *(uint4*)((char*)Xw[t >> 3] + XW_ZROW * 128 + (t & 7) * 16) = make_uint4(0, 0, 0, 0);

    f32x4 acc[4][4];
    {
        f32x4 z = {0.f, 0.f, 0.f, 0.f};
#pragma unroll
        for (int i = 0; i < 4; ++i)
#pragma unroll
            for (int j = 0; j < 4; ++j) acc[i][j] = z;
    }

    // prologue: window g0 + W(0), full drain once
    stageX(0, 0);
    stageW(0, 0);
    __syncthreads();   // vmcnt(0)+lgkmcnt(0)+barrier: zero rows + g0 + W0 visible

    // Issue schedule per tap t: W(t+1) [4], then Xw(g+1) [5] at t==0 / t==3.
    // In-order vmcnt => per-tap waits: {9,9,4,9,9,4,4,4,0} guarantee W(t) and Xw(t/3) landed.
#pragma unroll
    for (int tap = 0; tap < 9; ++tap) {
        const int g  = tap / 3;
        const int dy = g - 1;
        const int dx = tap - g * 3 - 1;

        // B1: all waves done computing tap-1 -> safe to overwrite As[(tap+1)&1] / Xw[(g+1)&1]
        __builtin_amdgcn_sched_barrier(0);
        __builtin_amdgcn_s_barrier();

        if (tap < 8) stageW(tap + 1, (tap + 1) & 1);
        if (tap == 0) stageX(1, 1);
        if (tap == 3) stageX(2, 0);
        __builtin_amdgcn_sched_barrier(0);
        if (tap == 0 || tap == 1 || tap == 3 || tap == 4)
            asm volatile("s_waitcnt vmcnt(9)" ::: "memory");
        else if (tap == 8)
            asm volatile("s_waitcnt vmcnt(0)" ::: "memory");
        else
            asm volatile("s_waitcnt vmcnt(4)" ::: "memory");
        __builtin_amdgcn_sched_barrier(0);

        // B2: every wave passed its counted wait -> all of tap's operands in LDS
        __builtin_amdgcn_s_barrier();

        // boundary: redirect invalid rows to the zero row
        int ro[4];
#pragma unroll
        for (int ni = 0; ni < 4; ++ni) {
            bool ok = ((unsigned)(hh[ni] + dy) < HW) & ((unsigned)(wwp[ni] + dx) < HW);
            ro[ni] = ok ? (rbase[ni] + dx) : XW_ZROW;
        }

        const char* Ab = (const char*)As[tap & 1];
        const char* Xb = (const char*)Xw[g & 1];
#pragma unroll
        for (int kh = 0; kh < 2; ++kh) {
            const int cc = kh * 4 + lq;
            bf16x8 a_frag[4], b_frag[4];
#pragma unroll
            for (int mi = 0; mi < 4; ++mi) {
                int R = oc_base + mi * 16 + lr;
                a_frag[mi] = *(const bf16x8*)(Ab + R * 128 + ((cc ^ (R & 7)) * 16));
            }
#pragma unroll
            for (int ni = 0; ni < 4; ++ni)
                b_frag[ni] = *(const bf16x8*)(Xb + ro[ni] * 128 + ((cc ^ (ro[ni] & 7)) * 16));
            __builtin_amdgcn_s_setprio(1);
#pragma unroll
            for (int mi = 0; mi < 4; ++mi)
#pragma unroll
                for (int ni = 0; ni < 4; ++ni)
                    acc[mi][ni] = __builtin_amdgcn_mfma_f32_16x16x32_bf16(
                        a_frag[mi], b_frag[ni], acc[mi][ni], 0, 0, 0);
            __builtin_amdgcn_s_setprio(0);
        }
    }

    // ---- epilogue: D col = lane&15 -> pixel, row = lq*4+reg -> oc (validated R1)
#pragma unroll
    for (int mi = 0; mi < 4; ++mi) {
#pragma unroll
        for (int rg = 0; rg < 4; ++rg) {
            const int oc = oc_base + mi * 16 + lq * 4 + rg;
            const float bb = bias[oc];
            float* orow = out + ((size_t)n_img * OCN + oc) * PIX + p0 + px_base + lr;
#pragma unroll
            for (int ni = 0; ni < 4; ++ni)
                orow[ni * 16] = acc[mi][ni][rg] + bb;
        }
    }
}

extern "C" void kernel_launch(void* const* d_in, const int* in_sizes, int n_in,
                              void* d_out, int out_size, void* d_ws, size_t ws_size,
                              hipStream_t stream) {
    const float* x    = (const float*)d_in[0];
    const float* w    = (const float*)d_in[1];
    const float* bias = (const float*)d_in[2];
    float* out = (float*)d_out;
    uint8_t* ws = (uint8_t*)d_ws;   // needs ZG_OFF + 128 = 25,837,696 bytes

    prep<<<XBLK + WBLK, 256, 0, stream>>>(x, w, ws);
    conv_mfma<<<NBLK, 256, 0, stream>>>(ws, bias, out);
}

// Round 11
// 169.984 us; speedup vs baseline: 1.2524x; 1.0127x over previous
//
#include <hip/hip_runtime.h>
#include <stdint.h>

// 3x3 conv s1 p1, NCHW fp32, 64->128 ch, 16x112x112.
// Implicit GEMM on bf16 MFMA with NHWC bf16 x-repack in d_ws:
//   prep (R0-proven): x -> x_t[(n*12544+p)*64+ic] bf16 ; w -> Wt[tap][oc][ic] bf16 ; zero block.
//   conv (R9 kernel, third submit - R9/R10 both died to broker infra, never ran):
//     per block 128oc x 128px tile. Occupancy/de-phasing probe:
//     - 3 blocks/CU (49.5KB LDS): As dbuf 2x16KB (counted-vmcnt W pipeline, R5-proven) +
//       SINGLE exact per-dy X window (131 rows = 16.75KB; staged at each group boundary,
//       3x/block, exposed ~L2 latency each - cheap).
//     - Per-block dy-group ROTATION (grot = b%3): co-resident blocks traverse taps in
//       rotated order -> different W-taps/X-windows in flight at any instant (breaks the
//       identical-schedule phase-lock suspected of serializing L2/LDS/MFMA usage).
//     - Per-tap waits: vmcnt(4) steady (W(t) landed, W(t+1) in flight; at group boundaries
//       X issued BEFORE W so vmcnt(4) also proves X landed); vmcnt(0) at last tap.
//     - Boundary: staging OOB pixel -> zero block; tap h/w wrap -> zero row 130.
//     - XCD-chunked bijective block swizzle (1568 = 8*196). T5 setprio kept (free).

#define HW     112
#define PIX    12544
#define ICN    64
#define OCN    128
#define TILEP  128
#define PTILES 98
#define NBLK   1568
#define NIMG   16

#define XT_BYTES   (NIMG * PIX * ICN * 2)          // 25,690,112
#define WT_OFF     XT_BYTES
#define WT_BYTES   (9 * OCN * ICN * 2)             // 147,456
#define ZG_OFF     (WT_OFF + WT_BYTES)             // 128B zero block
#define XBLK       (NIMG * (PIX / 64))             // 3136 transpose blocks
#define WBLK       72                              // 72 * 1024 = 73728 weight elems

#define XW_ZROW    130                             // zero row index
#define XW_BYTES   (131 * 128)                     // 16,768

typedef __attribute__((ext_vector_type(8))) __bf16 bf16x8;
typedef __attribute__((ext_vector_type(4))) float  f32x4;

__device__ __forceinline__ uint32_t rne_lo(float f) {
    uint32_t u = __builtin_bit_cast(uint32_t, f);
    return (u + 0x7fffu + ((u >> 16) & 1u)) >> 16;
}
__device__ __forceinline__ uint32_t pk2(float a, float b) {
    uint32_t ub = __builtin_bit_cast(uint32_t, b);
    ub = (ub + 0x7fffu + ((ub >> 16) & 1u)) & 0xffff0000u;
    return rne_lo(a) | ub;
}

__device__ __forceinline__ void load_lds16(const void* g, void* l) {
    __builtin_amdgcn_global_load_lds(
        (const __attribute__((address_space(1))) uint32_t*)g,
        (__attribute__((address_space(3))) uint32_t*)l, 16, 0, 0);
}

// ---------------- prep: x transpose+cvt, weight transpose+cvt, zero block ----------------
__global__ void __launch_bounds__(256)
prep(const float* __restrict__ x, const float* __restrict__ w, uint8_t* __restrict__ ws) {
    const int b = blockIdx.x;
    const int t = threadIdx.x;
    uint16_t* xt = (uint16_t*)ws;
    uint16_t* wt = (uint16_t*)(ws + WT_OFF);

    if (b < XBLK) {
        // 64 pixels per block; thread: pixel = t>>2, ic chunk q = t&3 (16 ic each)
        const int n  = b / (PIX / 64);
        const int p0 = (b - n * (PIX / 64)) * 64;
        const int px = t >> 2;
        const int q  = t & 3;
        const float* src = x + ((size_t)n * ICN + q * 16) * PIX + p0 + px;
        float v[16];
#pragma unroll
        for (int i = 0; i < 16; ++i) v[i] = src[(size_t)i * PIX];
        uint4 u0 = make_uint4(pk2(v[0], v[1]),  pk2(v[2], v[3]),
                              pk2(v[4], v[5]),  pk2(v[6], v[7]));
        uint4 u1 = make_uint4(pk2(v[8], v[9]),  pk2(v[10], v[11]),
                              pk2(v[12], v[13]), pk2(v[14], v[15]));
        char* dst = (char*)xt + ((size_t)(n * PIX + p0 + px)) * 128 + q * 32;
        *(uint4*)dst        = u0;
        *(uint4*)(dst + 16) = u1;
    } else {
        const int wb = b - XBLK;
#pragma unroll
        for (int k = 0; k < 4; ++k) {
            int wi = wb * 1024 + k * 256 + t;          // [0, 73728)
            int r  = wi >> 13;
            int oc = (wi >> 6) & 127;
            int ic = wi & 63;
            wt[wi] = (uint16_t)rne_lo(w[oc * 576 + ic * 9 + r]);
        }
        if (wb == 0 && t < 8) ((uint4*)(ws + ZG_OFF))[t] = make_uint4(0, 0, 0, 0);
    }
}

// ---------------- main conv ----------------
__global__ void __launch_bounds__(256, 3)
conv_mfma(const uint8_t* __restrict__ ws, const float* __restrict__ bias,
          float* __restrict__ out) {
    __shared__ uint16_t As[2][8192];                   // W, dbuf, 16KB each
    __shared__ __align__(16) uint8_t Xw[XW_BYTES];     // X per-dy window, single buffer

    const char* xt = (const char*)ws;
    const char* wt = (const char*)(ws + WT_OFF);
    const char* zg = (const char*)(ws + ZG_OFF);

    const int t = threadIdx.x;
    // Bijective XCD-chunked swizzle: XCD k (blockIdx%8) gets contiguous tile ids.
    const int b = (blockIdx.x & 7) * (NBLK / 8) + (blockIdx.x >> 3);
    const int n_img = b / PTILES;
    const int p0 = (b - n_img * PTILES) * TILEP;
    const int grot = b % 3;                            // per-block dy-group rotation

    const int lane = t & 63;
    const int wave = t >> 6;
    const int lr = lane & 15;
    const int lq = lane >> 4;
    const int oc_base = (wave & 1) * 64;
    const int px_base = (wave >> 1) * 64;

    // ---- staging geometry: row = r2*32 + (t>>3); chunk pos = t&7, src chunk XOR-swizzled
    const int rowB = t >> 3;                   // 0..31
    const int cswz = (t & 7) ^ (rowB & 7);     // row&7 == rowB&7 (pass*32 = 0 mod 8)
    const char* xsrcX  = xt + ((size_t)n_img * PIX) * 128 + cswz * 16;  // + pw*128
    const char* waddr0 = wt + rowB * 128 + cswz * 16;
    const char* zaddr  = zg + (t & 7) * 16;

    // ---- per-ni output-pixel geometry; window row = (p - p0) + 1 + dx (dy-independent) ----
    int hh[4], wwp[4], rbase[4];
#pragma unroll
    for (int ni = 0; ni < 4; ++ni) {
        int po = px_base + ni * 16 + lr;
        int p  = p0 + po;
        int h  = p / HW;
        hh[ni]   = h;
        wwp[ni]  = p - h * HW;
        rbase[ni] = po + 1;
    }

    // stage W for weight-tap tw -> As[bsel]: 4 loads/thread (16KB)
    auto stageW = [&](int tw, int bsel) {
#pragma unroll
        for (int r2 = 0; r2 < 4; ++r2)
            load_lds16(waddr0 + tw * 16384 + r2 * 4096,
                       (char*)As[bsel] + r2 * 4096 + wave * 1024);
    };
    // stage X window for effective dy-group ge (rows 0..129; OOB pixels -> zero block)
    auto stageX = [&](int ge) {
        const int pwb = p0 + (ge - 1) * HW - 1;        // window row 0 = pixel pwb
#pragma unroll
        for (int r2 = 0; r2 < 4; ++r2) {
            int pw = pwb + r2 * 32 + rowB;
            const char* gp = ((unsigned)pw < PIX) ? (xsrcX + (ptrdiff_t)pw * 128) : zaddr;
            load_lds16(gp, (char*)Xw + r2 * 4096 + wave * 1024);
        }
        if (rowB < 2) {                                // rows 128,129 (wave 0, lanes 0..15)
            int pw = pwb + 128 + rowB;
            const char* gp = ((unsigned)pw < PIX) ? (xsrcX + (ptrdiff_t)pw * 128) : zaddr;
            load_lds16(gp, (char*)Xw + 4 * 4096 + wave * 1024);
        }
    };

    // zero row (slot 130; staging never touches it)
    if (t < 8)
        *(uint4*)((char*)Xw + XW_ZROW * 128 + t * 16) = make_uint4(0, 0, 0, 0);

    f32x4 acc[4][4];
    {
        f32x4 z = {0.f, 0.f, 0.f, 0.f};
#pragma unroll
        for (int i = 0; i < 4; ++i)
#pragma unroll
            for (int j = 0; j < 4; ++j) acc[i][j] = z;
    }

    // prologue: first window + first W, full drain once
    {
        const int ge0 = grot;                          // gslot 0 -> g_eff = grot
        stageX(ge0);
        stageW(ge0 * 3, 0);
    }
    __syncthreads();   // vmcnt(0)+lgkmcnt(0)+barrier: zero row + X(g0) + W(t0) visible

#pragma unroll
    for (int j = 0; j < 9; ++j) {
        const int gslot = j / 3;
        const int ge    = (gslot + grot) % 3;          // effective dy-group
        const int dy    = ge - 1;
        const int dx    = (j - gslot * 3) - 1;
        const bool gb   = (j == 3 || j == 6);          // group boundary: restage window

        // B1: all waves done computing tap j-1 -> safe to overwrite As[(j+1)&1];
        //     at boundaries also done reading the old window -> safe to overwrite Xw.
        __builtin_amdgcn_sched_barrier(0);
        __builtin_amdgcn_s_barrier();

        if (gb) stageX(ge);                            // X first (oldest in vmcnt order)
        if (j < 8) {
            const int jn = j + 1;
            const int gn = jn / 3;
            stageW(((gn + grot) % 3) * 3 + (jn - gn * 3), jn & 1);
        }
        __builtin_amdgcn_sched_barrier(0);
        // vmcnt(4): W(j+1)'s 4 loads may remain in flight; everything older (W(j), and
        // X(ge) when staged this tap) has landed. Last tap: drain.
        if (j < 8) asm volatile("s_waitcnt vmcnt(4)" ::: "memory");
        else       asm volatile("s_waitcnt vmcnt(0)" ::: "memory");
        __builtin_amdgcn_sched_barrier(0);

        // B2: every wave passed its counted wait -> all of tap j's operands in LDS
        __builtin_amdgcn_s_barrier();

        // boundary: redirect invalid rows to the zero row
        int ro[4];
#pragma unroll
        for (int ni = 0; ni < 4; ++ni) {
            bool ok = ((unsigned)(hh[ni] + dy) < HW) & ((unsigned)(wwp[ni] + dx) < HW);
            ro[ni] = ok ? (rbase[ni] + dx) : XW_ZROW;
        }

        const char* Ab = (const char*)As[j & 1];
#pragma unroll
        for (int kh = 0; kh < 2; ++kh) {
            const int cc = kh * 4 + lq;
            bf16x8 a_frag[4], b_frag[4];
#pragma unroll
            for (int mi = 0; mi < 4; ++mi) {
                int R = oc_base + mi * 16 + lr;
                a_frag[mi] = *(const bf16x8*)(Ab + R * 128 + ((cc ^ (R & 7)) * 16));
            }
#pragma unroll
            for (int ni = 0; ni < 4; ++ni)
                b_frag[ni] = *(const bf16x8*)((const char*)Xw + ro[ni] * 128
                                              + ((cc ^ (ro[ni] & 7)) * 16));
            __builtin_amdgcn_s_setprio(1);
#pragma unroll
            for (int mi = 0; mi < 4; ++mi)
#pragma unroll
                for (int ni = 0; ni < 4; ++ni)
                    acc[mi][ni] = __builtin_amdgcn_mfma_f32_16x16x32_bf16(
                        a_frag[mi], b_frag[ni], acc[mi][ni], 0, 0, 0);
            __builtin_amdgcn_s_setprio(0);
        }
    }

    // ---- epilogue: D col = lane&15 -> pixel, row = lq*4+reg -> oc (validated R1)
#pragma unroll
    for (int mi = 0; mi < 4; ++mi) {
#pragma unroll
        for (int rg = 0; rg < 4; ++rg) {
            const int oc = oc_base + mi * 16 + lq * 4 + rg;
            const float bb = bias[oc];
            float* orow = out + ((size_t)n_img * OCN + oc) * PIX + p0 + px_base + lr;
#pragma unroll
            for (int ni = 0; ni < 4; ++ni)
                orow[ni * 16] = acc[mi][ni][rg] + bb;
        }
    }
}

extern "C" void kernel_launch(void* const* d_in, const int* in_sizes, int n_in,
                              void* d_out, int out_size, void* d_ws, size_t ws_size,
                              hipStream_t stream) {
    const float* x    = (const float*)d_in[0];
    const float* w    = (const float*)d_in[1];
    const float* bias = (const float*)d_in[2];
    float* out = (float*)d_out;
    uint8_t* ws = (uint8_t*)d_ws;   // needs ZG_OFF + 128 = 25,837,696 bytes

    prep<<<XBLK + WBLK, 256, 0, stream>>>(x, w, ws);
    conv_mfma<<<NBLK, 256, 0, stream>>>(ws, bias, out);
}